// Round 10
// baseline (2406.472 us; speedup 1.0000x reference)
//
#include <hip/hip_runtime.h>
#include <hip/hip_bf16.h>

#define BSz 2
#define Nn 15135
#define Ee 242160
#define F_INc 8
#define Hh 64
#define Ll 4
#define HFCc 256
#define NCc 10
#define EPSg 1e-15f
#define NBLK ((Nn + 255) / 256)   // 60 scan blocks

__device__ __forceinline__ float uf(unsigned u) { return __uint_as_float(u); }
__device__ __forceinline__ unsigned short bs16(float f) {
    unsigned b = __float_as_uint(f);
    return (unsigned short)((b + 0x7FFFu + ((b >> 16) & 1u)) >> 16);
}
__device__ __forceinline__ unsigned packbf(float a, float b) {
    return (unsigned)bs16(a) | ((unsigned)bs16(b) << 16);
}

// ---- init ----------------------------------------------------------------

__global__ void zero_kernel(int* __restrict__ cursor, float* __restrict__ h1acc) {
    int i = blockIdx.x * 256 + threadIdx.x;
    if (i < Nn) cursor[i] = 0;
    if (i < BSz * HFCc) h1acc[i] = 0.f;
}

// x (2,N,8) f32 -> xi[n*8+f] = packed bf16 {b0,b1}
__global__ void pack_x(const float* __restrict__ x, unsigned* __restrict__ xi) {
    int i = blockIdx.x * 256 + threadIdx.x;
    if (i < Nn * F_INc) xi[i] = packbf(x[i], x[(size_t)Nn * F_INc + i]);
}

// ---- CSR build ----------------------------------------------------------

__global__ void count_kernel(const int* __restrict__ dst, int* __restrict__ cnt) {
    int e = blockIdx.x * blockDim.x + threadIdx.x;
    if (e < Ee) atomicAdd(&cnt[dst[e]], 1);
}

__global__ void scan_local(const int* __restrict__ cnt, int* __restrict__ loc,
                           int* __restrict__ bsum) {
    int tid = threadIdx.x, lane = tid & 63, w = tid >> 6;
    int i = blockIdx.x * 256 + tid;
    __shared__ int ws[4];
    int v = (i < Nn) ? cnt[i] : 0;
    int incl = v;
#pragma unroll
    for (int d = 1; d < 64; d <<= 1) {
        int t = __shfl_up(incl, d, 64);
        if (lane >= d) incl += t;
    }
    if (lane == 63) ws[w] = incl;
    __syncthreads();
    int pre = 0;
    for (int ww = 0; ww < w; ++ww) pre += ws[ww];
    if (i < Nn) loc[i] = pre + incl - v;
    if (tid == 255) bsum[blockIdx.x] = pre + incl;
}

__global__ void scan_tops(int* __restrict__ bsum) {
    int lane = threadIdx.x;
    int v = (lane < NBLK) ? bsum[lane] : 0;
    int incl = v;
#pragma unroll
    for (int d = 1; d < 64; d <<= 1) {
        int t = __shfl_up(incl, d, 64);
        if (lane >= d) incl += t;
    }
    if (lane < NBLK) bsum[lane] = incl - v;
}

__global__ void scan_fix(const int* __restrict__ loc, const int* __restrict__ bsum,
                         int* __restrict__ offs, int* __restrict__ cursor) {
    int i = blockIdx.x * 256 + threadIdx.x;
    if (i < Nn) {
        int o = loc[i] + bsum[blockIdx.x];
        offs[i] = o;
        cursor[i] = o;
    }
    if (i == 0) offs[Nn] = Ee;
}

// fill CSR + per-layer gauss arrays gauss[l*E + p]
__global__ void fill_kernel(const int* __restrict__ src, const int* __restrict__ dst,
                            const float* __restrict__ pseudo, int* __restrict__ cursor,
                            int* __restrict__ csr_src, float2* __restrict__ gauss,
                            const float* __restrict__ mu1, const float* __restrict__ sigma1,
                            const float* __restrict__ mus, const float* __restrict__ sigmas) {
    int e = blockIdx.x * blockDim.x + threadIdx.x;
    if (e >= Ee) return;
    int p = atomicAdd(&cursor[dst[e]], 1);
    csr_src[p] = src[e];
    float2 ps = ((const float2*)pseudo)[e];
#pragma unroll
    for (int l = 0; l < Ll; ++l) {
        const float* mu = (l == 0) ? mu1 : mus + (l - 1) * 4;
        const float* sg = (l == 0) ? sigma1 : sigmas + (l - 1) * 4;
        float d00 = ps.x - mu[0], d01 = ps.y - mu[1];
        float d10 = ps.x - mu[2], d11 = ps.y - mu[3];
        float i00 = 1.f / (EPSg + sg[0] * sg[0]);
        float i01 = 1.f / (EPSg + sg[1] * sg[1]);
        float i10 = 1.f / (EPSg + sg[2] * sg[2]);
        float i11 = 1.f / (EPSg + sg[3] * sg[3]);
        float g0 = expf(-0.5f * (d00 * d00 * i00 + d01 * d01 * i01));
        float g1 = expf(-0.5f * (d10 * d10 * i10 + d11 * d11 * i11));
        gauss[(size_t)l * Ee + p] = make_float2(g0, g1);
    }
}

// ---- gather_agg layer 0: xi rows (8 uints), 8 edges per wave-iteration ---
__global__ void gather_agg0(const unsigned* __restrict__ xi, const int* __restrict__ offs,
                            const int* __restrict__ csr_src, const float2* __restrict__ gauss,
                            unsigned* __restrict__ agg) {
    int tid = threadIdx.x;
    int lane = tid & 63;
    int n = blockIdx.x * 4 + (tid >> 6);
    if (n >= Nn) return;
    int esub = lane >> 3, f = lane & 7;
    int s0 = offs[n], s1 = offs[n + 1];
    float a00 = 0.f, a01 = 0.f, a10 = 0.f, a11 = 0.f;  // a[k][b]
    if (s1 > s0) {
        int last = s1 - 1;
        for (int p0 = s0; p0 <= last; p0 += 8) {
            int p = p0 + esub;
            int pc = p < last ? p : last;
            float2 g = gauss[pc];
            if (p > last) { g.x = 0.f; g.y = 0.f; }
            unsigned u = xi[csr_src[pc] * F_INc + f];
            float x0 = uf(u << 16), x1 = uf(u & 0xFFFF0000u);
            a00 += g.x * x0; a01 += g.x * x1;
            a10 += g.y * x0; a11 += g.y * x1;
        }
#pragma unroll
        for (int d = 8; d <= 32; d <<= 1) {
            a00 += __shfl_xor(a00, d, 64);
            a01 += __shfl_xor(a01, d, 64);
            a10 += __shfl_xor(a10, d, 64);
            a11 += __shfl_xor(a11, d, 64);
        }
    }
    if (lane < 8) {
        agg[(size_t)n * 16 + f]     = packbf(a00, a01);
        agg[(size_t)n * 16 + 8 + f] = packbf(a10, a11);
    }
}

// ---- gather_agg layers 1..3: packed h rows (64 uints = 256 B, L2-resident)
__global__ void gather_agg(const unsigned* __restrict__ hp, const int* __restrict__ offs,
                           const int* __restrict__ csr_src, const float2* __restrict__ gauss,
                           unsigned* __restrict__ agg) {
    int tid = threadIdx.x;
    int lane = tid & 63;
    int n = blockIdx.x * 4 + (tid >> 6);
    if (n >= Nn) return;
    int s0 = offs[n], s1 = offs[n + 1];
    float a00 = 0.f, a01 = 0.f, a10 = 0.f, a11 = 0.f;  // a[k][b]
    int p = s0;
    for (; p + 3 < s1; p += 4) {
        int sa = csr_src[p], sb = csr_src[p + 1], sc = csr_src[p + 2], sd = csr_src[p + 3];
        float2 ga = gauss[p], gb = gauss[p + 1], gc = gauss[p + 2], gd = gauss[p + 3];
        unsigned ua = hp[(size_t)sa * 64 + lane];
        unsigned ub = hp[(size_t)sb * 64 + lane];
        unsigned uc = hp[(size_t)sc * 64 + lane];
        unsigned ud = hp[(size_t)sd * 64 + lane];
        float xa0 = uf(ua << 16), xa1 = uf(ua & 0xFFFF0000u);
        float xb0 = uf(ub << 16), xb1 = uf(ub & 0xFFFF0000u);
        float xc0 = uf(uc << 16), xc1 = uf(uc & 0xFFFF0000u);
        float xd0 = uf(ud << 16), xd1 = uf(ud & 0xFFFF0000u);
        a00 += ga.x * xa0 + gb.x * xb0 + gc.x * xc0 + gd.x * xd0;
        a01 += ga.x * xa1 + gb.x * xb1 + gc.x * xc1 + gd.x * xd1;
        a10 += ga.y * xa0 + gb.y * xb0 + gc.y * xc0 + gd.y * xd0;
        a11 += ga.y * xa1 + gb.y * xb1 + gc.y * xc1 + gd.y * xd1;
    }
    for (; p < s1; ++p) {
        int sa = csr_src[p];
        float2 ga = gauss[p];
        unsigned ua = hp[(size_t)sa * 64 + lane];
        float xa0 = uf(ua << 16), xa1 = uf(ua & 0xFFFF0000u);
        a00 += ga.x * xa0; a01 += ga.x * xa1;
        a10 += ga.y * xa0; a11 += ga.y * xa1;
    }
    agg[(size_t)n * 128 + lane]      = packbf(a00, a01);
    agg[(size_t)n * 128 + 64 + lane] = packbf(a10, a11);
}

// ---- combine: per-node GEMM agg@G + prev@root + bias, ELU, fc reduce -----
// agg layout [n][k*FP+f] packed {b0,b1}; G[f*128 + k*64 + h]; root[f*64 + h]
template<int FP>
__global__ void combine_kernel(const unsigned* __restrict__ agg, const int* __restrict__ offs,
                               const unsigned* __restrict__ prevp, const float* __restrict__ G,
                               const float* __restrict__ root, const float* __restrict__ bias,
                               const float* __restrict__ fc_w, int l,
                               unsigned* __restrict__ hpout, float* __restrict__ node) {
    int tid = threadIdx.x;
    int h = tid & 63;
    int r = tid >> 6;
    int n0 = blockIdx.x * 4;
    int n = n0 + r;
    __shared__ unsigned s_agg[4][2 * FP];
    __shared__ unsigned s_prev[4][FP];
    for (int idx = tid; idx < 4 * 2 * FP; idx += 256) {
        int rr = idx / (2 * FP), ff = idx % (2 * FP);
        int gn = n0 + rr;
        s_agg[rr][ff] = (gn < Nn) ? agg[(size_t)gn * 2 * FP + ff] : 0u;
    }
    for (int idx = tid; idx < 4 * FP; idx += 256) {
        int rr = idx / FP, ff = idx % FP;
        int gn = n0 + rr;
        s_prev[rr][ff] = (gn < Nn) ? prevp[(size_t)gn * FP + ff] : 0u;
    }
    __syncthreads();
    if (n >= Nn) return;
    float dg = (float)(offs[n + 1] - offs[n]);
    if (dg < 1.f) dg = 1.f;
    float inv = 1.f / dg;
    float bv = bias[h];
    float aA0 = 0.f, aA1 = 0.f;
    float aR0 = bv, aR1 = bv;
#pragma unroll
    for (int f = 0; f < FP; ++f) {
        float rv = root[f * 64 + h];
        unsigned up = s_prev[r][f];
        aR0 = fmaf(uf(up << 16), rv, aR0);
        aR1 = fmaf(uf(up & 0xFFFF0000u), rv, aR1);
    }
#pragma unroll
    for (int k = 0; k < 2; ++k) {
#pragma unroll
        for (int f = 0; f < FP; ++f) {
            float gv = G[f * 128 + k * 64 + h];
            unsigned ua = s_agg[r][k * FP + f];
            aA0 = fmaf(uf(ua << 16), gv, aA0);
            aA1 = fmaf(uf(ua & 0xFFFF0000u), gv, aA1);
        }
    }
    float val0 = fmaf(aA0, inv, aR0);
    float val1 = fmaf(aA1, inv, aR1);
    val0 = val0 > 0.f ? val0 : expm1f(val0);
    val1 = val1 > 0.f ? val1 : expm1f(val1);
    hpout[(size_t)n * 64 + h] = packbf(val0, val1);
    float fw = fc_w[h * Ll + l];
    float r0 = val0 * fw, r1 = val1 * fw;
#pragma unroll
    for (int off = 32; off; off >>= 1) {
        r0 += __shfl_down(r0, off, 64);
        r1 += __shfl_down(r1, off, 64);
    }
    if (h == 0) {
        if (l == 0) { node[n] = r0; node[Nn + n] = r1; }
        else        { node[n] += r0; node[Nn + n] += r1; }
    }
}

// ---- head ----------------------------------------------------------------

__global__ void lin1_kernel(const float* __restrict__ node, const float* __restrict__ w,
                            const float* __restrict__ fcb, float* __restrict__ h1acc) {
    int hfc = threadIdx.x;
    int n0 = blockIdx.x * 64;
    int nend = n0 + 64 < Nn ? n0 + 64 : Nn;
    float fb = fcb[0];
    float a0 = 0.f, a1 = 0.f;
    for (int n = n0; n < nend; ++n) {
        float wv = w[(size_t)n * HFCc + hfc];
        a0 += (node[n] + fb) * wv;
        a1 += (node[Nn + n] + fb) * wv;
    }
    atomicAdd(&h1acc[hfc], a0);
    atomicAdd(&h1acc[HFCc + hfc], a1);
}

__global__ void head_kernel(const float* __restrict__ h1acc, const float* __restrict__ l1b,
                            const float* __restrict__ w2, const float* __restrict__ b2,
                            float* __restrict__ out) {
    __shared__ float sh[HFCc];
    __shared__ float slog[NCc];
    __shared__ float s_lse;
    int tid = threadIdx.x;
    for (int b = 0; b < BSz; ++b) {
        float v = h1acc[b * HFCc + tid] + l1b[tid];
        v = v > 0.f ? v : expm1f(v);
        sh[tid] = v;
        __syncthreads();
        if (tid < NCc) {
            float s = b2[tid];
            for (int i = 0; i < HFCc; ++i) s += sh[i] * w2[i * NCc + tid];
            slog[tid] = s;
        }
        __syncthreads();
        if (tid == 0) {
            float m = slog[0];
            for (int c = 1; c < NCc; ++c) m = fmaxf(m, slog[c]);
            float se = 0.f;
            for (int c = 0; c < NCc; ++c) se += expf(slog[c] - m);
            s_lse = m + logf(se);
        }
        __syncthreads();
        if (tid < NCc) out[b * NCc + tid] = slog[tid] - s_lse;
        __syncthreads();
    }
}

extern "C" void kernel_launch(void* const* d_in, const int* in_sizes, int n_in,
                              void* d_out, int out_size, void* d_ws, size_t ws_size,
                              hipStream_t stream) {
    const float* x      = (const float*)d_in[0];
    const int*   ei     = (const int*)d_in[2];
    const float* pseudo = (const float*)d_in[3];
    const float* g1     = (const float*)d_in[4];
    const float* mu1    = (const float*)d_in[5];
    const float* sigma1 = (const float*)d_in[6];
    const float* root1  = (const float*)d_in[7];
    const float* b1     = (const float*)d_in[8];
    const float* gs     = (const float*)d_in[9];
    const float* mus    = (const float*)d_in[10];
    const float* sigmas = (const float*)d_in[11];
    const float* roots  = (const float*)d_in[12];
    const float* bs_p   = (const float*)d_in[13];
    const float* fc_w   = (const float*)d_in[14];
    const float* fc_b   = (const float*)d_in[15];
    const float* lin1_w = (const float*)d_in[16];
    const float* lin1_b = (const float*)d_in[17];
    const float* lin2_w = (const float*)d_in[18];
    const float* lin2_b = (const float*)d_in[19];
    float* out = (float*)d_out;

    const int* src = ei;
    const int* dst = ei + Ee;

    auto alignup = [](size_t v) { return (v + 255) & ~(size_t)255; };
    char* ws = (char*)d_ws;
    size_t off = 0;
    float*    node    = (float*)(ws + off);    off += alignup((size_t)BSz * Nn * 4);
    float*    h1acc   = (float*)(ws + off);    off += alignup((size_t)BSz * HFCc * 4);
    int*      offs    = (int*)(ws + off);      off += alignup((size_t)(Nn + 1) * 4);
    int*      cursor  = (int*)(ws + off);      off += alignup((size_t)Nn * 4);
    int*      loc     = (int*)(ws + off);      off += alignup((size_t)Nn * 4);
    int*      bsum    = (int*)(ws + off);      off += alignup((size_t)64 * 4);
    int*      csr_src = (int*)(ws + off);      off += alignup((size_t)Ee * 4);
    float2*   gauss   = (float2*)(ws + off);   off += alignup((size_t)Ll * Ee * 8);
    unsigned* xi      = (unsigned*)(ws + off); off += alignup((size_t)Nn * F_INc * 4);
    unsigned* agg     = (unsigned*)(ws + off); off += alignup((size_t)Nn * 128 * 4);
    unsigned* hpA     = (unsigned*)(ws + off); off += alignup((size_t)Nn * 64 * 4);
    unsigned* hpB     = (unsigned*)(ws + off); off += alignup((size_t)Nn * 64 * 4);
    (void)ws_size; (void)in_sizes; (void)n_in; (void)out_size;

    zero_kernel<<<NBLK, 256, 0, stream>>>(cursor, h1acc);
    count_kernel<<<(Ee + 255) / 256, 256, 0, stream>>>(dst, cursor);
    scan_local<<<NBLK, 256, 0, stream>>>(cursor, loc, bsum);
    scan_tops<<<1, 64, 0, stream>>>(bsum);
    scan_fix<<<NBLK, 256, 0, stream>>>(loc, bsum, offs, cursor);
    pack_x<<<(Nn * F_INc + 255) / 256, 256, 0, stream>>>(x, xi);
    fill_kernel<<<(Ee + 255) / 256, 256, 0, stream>>>(src, dst, pseudo, cursor, csr_src, gauss,
                                                      mu1, sigma1, mus, sigmas);

    int ngrid = (Nn + 3) / 4;

    // layer 0
    gather_agg0<<<ngrid, 256, 0, stream>>>(xi, offs, csr_src, gauss, agg);
    combine_kernel<F_INc><<<ngrid, 256, 0, stream>>>(agg, offs, xi, g1, root1, b1, fc_w,
                                                     0, hpA, node);
    // layers 1..3
    unsigned* prev = hpA;
    unsigned* next = hpB;
    for (int l = 1; l < Ll; ++l) {
        const float* G  = gs    + (size_t)(l - 1) * Hh * 128;
        const float* rt = roots + (size_t)(l - 1) * Hh * Hh;
        const float* bb = bs_p  + (size_t)(l - 1) * Hh;
        gather_agg<<<ngrid, 256, 0, stream>>>(prev, offs, csr_src, gauss + (size_t)l * Ee, agg);
        combine_kernel<Hh><<<ngrid, 256, 0, stream>>>(agg, offs, prev, G, rt, bb, fc_w,
                                                      l, next, node);
        unsigned* t = prev; prev = next; next = t;
    }

    lin1_kernel<<<(Nn + 63) / 64, 256, 0, stream>>>(node, lin1_w, fc_b, h1acc);
    head_kernel<<<1, HFCc, 0, stream>>>(h1acc, lin1_b, lin2_w, lin2_b, out);
}

// Round 11
// 240.430 us; speedup vs baseline: 10.0090x; 10.0090x over previous
//
#include <hip/hip_runtime.h>
#include <hip/hip_bf16.h>

#define BSz 2
#define Nn 15135
#define Ee 242160
#define F_INc 8
#define Hh 64
#define Ll 4
#define HFCc 256
#define NCc 10
#define EPSg 1e-15f
#define NBLK ((Nn + 255) / 256)   // 60 scan blocks

__device__ __forceinline__ float uf(unsigned u) { return __uint_as_float(u); }
__device__ __forceinline__ unsigned short bs16(float f) {
    unsigned b = __float_as_uint(f);
    return (unsigned short)((b + 0x7FFFu + ((b >> 16) & 1u)) >> 16);
}
__device__ __forceinline__ unsigned packbf(float a, float b) {
    return (unsigned)bs16(a) | ((unsigned)bs16(b) << 16);
}

// ---- init ----------------------------------------------------------------

__global__ void zero_kernel(int* __restrict__ cursor, float* __restrict__ h1acc) {
    int i = blockIdx.x * 256 + threadIdx.x;
    if (i < Nn) cursor[i] = 0;
    if (i < BSz * HFCc) h1acc[i] = 0.f;
}

// x (2,N,8) f32 -> xi[n*8+f] = packed bf16 {b0,b1}
__global__ void pack_x(const float* __restrict__ x, unsigned* __restrict__ xi) {
    int i = blockIdx.x * 256 + threadIdx.x;
    if (i < Nn * F_INc) xi[i] = packbf(x[i], x[(size_t)Nn * F_INc + i]);
}

// ---- CSR build ----------------------------------------------------------

__global__ void count_kernel(const int* __restrict__ dst, int* __restrict__ cnt) {
    int e = blockIdx.x * blockDim.x + threadIdx.x;
    if (e < Ee) atomicAdd(&cnt[dst[e]], 1);
}

__global__ void scan_local(const int* __restrict__ cnt, int* __restrict__ loc,
                           int* __restrict__ bsum) {
    int tid = threadIdx.x, lane = tid & 63, w = tid >> 6;
    int i = blockIdx.x * 256 + tid;
    __shared__ int ws[4];
    int v = (i < Nn) ? cnt[i] : 0;
    int incl = v;
#pragma unroll
    for (int d = 1; d < 64; d <<= 1) {
        int t = __shfl_up(incl, d, 64);
        if (lane >= d) incl += t;
    }
    if (lane == 63) ws[w] = incl;
    __syncthreads();
    int pre = 0;
    for (int ww = 0; ww < w; ++ww) pre += ws[ww];
    if (i < Nn) loc[i] = pre + incl - v;
    if (tid == 255) bsum[blockIdx.x] = pre + incl;
}

__global__ void scan_tops(int* __restrict__ bsum) {
    int lane = threadIdx.x;
    int v = (lane < NBLK) ? bsum[lane] : 0;
    int incl = v;
#pragma unroll
    for (int d = 1; d < 64; d <<= 1) {
        int t = __shfl_up(incl, d, 64);
        if (lane >= d) incl += t;
    }
    if (lane < NBLK) bsum[lane] = incl - v;
}

__global__ void scan_fix(const int* __restrict__ loc, const int* __restrict__ bsum,
                         int* __restrict__ offs, int* __restrict__ cursor) {
    int i = blockIdx.x * 256 + threadIdx.x;
    if (i < Nn) {
        int o = loc[i] + bsum[blockIdx.x];
        offs[i] = o;
        cursor[i] = o;
    }
    if (i == 0) offs[Nn] = Ee;
}

// fill CSR + per-layer gauss arrays gauss[l*E + p]
__global__ void fill_kernel(const int* __restrict__ src, const int* __restrict__ dst,
                            const float* __restrict__ pseudo, int* __restrict__ cursor,
                            int* __restrict__ csr_src, float2* __restrict__ gauss,
                            const float* __restrict__ mu1, const float* __restrict__ sigma1,
                            const float* __restrict__ mus, const float* __restrict__ sigmas) {
    int e = blockIdx.x * blockDim.x + threadIdx.x;
    if (e >= Ee) return;
    int p = atomicAdd(&cursor[dst[e]], 1);
    csr_src[p] = src[e];
    float2 ps = ((const float2*)pseudo)[e];
#pragma unroll
    for (int l = 0; l < Ll; ++l) {
        const float* mu = (l == 0) ? mu1 : mus + (l - 1) * 4;
        const float* sg = (l == 0) ? sigma1 : sigmas + (l - 1) * 4;
        float d00 = ps.x - mu[0], d01 = ps.y - mu[1];
        float d10 = ps.x - mu[2], d11 = ps.y - mu[3];
        float i00 = 1.f / (EPSg + sg[0] * sg[0]);
        float i01 = 1.f / (EPSg + sg[1] * sg[1]);
        float i10 = 1.f / (EPSg + sg[2] * sg[2]);
        float i11 = 1.f / (EPSg + sg[3] * sg[3]);
        float g0 = expf(-0.5f * (d00 * d00 * i00 + d01 * d01 * i01));
        float g1 = expf(-0.5f * (d10 * d10 * i10 + d11 * d11 * i11));
        gauss[(size_t)l * Ee + p] = make_float2(g0, g1);
    }
}

// ---- gather_agg layer 0: xi rows (8 uints), 8 edges per wave-iteration ---
__global__ void gather_agg0(const unsigned* __restrict__ xi, const int* __restrict__ offs,
                            const int* __restrict__ csr_src, const float2* __restrict__ gauss,
                            unsigned* __restrict__ agg) {
    int tid = threadIdx.x;
    int lane = tid & 63;
    int n = blockIdx.x * 4 + (tid >> 6);
    if (n >= Nn) return;
    int esub = lane >> 3, f = lane & 7;
    int s0 = offs[n], s1 = offs[n + 1];
    float a00 = 0.f, a01 = 0.f, a10 = 0.f, a11 = 0.f;  // a[k][b]
    if (s1 > s0) {
        int last = s1 - 1;
        for (int p0 = s0; p0 <= last; p0 += 8) {
            int p = p0 + esub;
            int pc = p < last ? p : last;
            float2 g = gauss[pc];
            if (p > last) { g.x = 0.f; g.y = 0.f; }
            unsigned u = xi[csr_src[pc] * F_INc + f];
            float x0 = uf(u << 16), x1 = uf(u & 0xFFFF0000u);
            a00 += g.x * x0; a01 += g.x * x1;
            a10 += g.y * x0; a11 += g.y * x1;
        }
#pragma unroll
        for (int d = 8; d <= 32; d <<= 1) {
            a00 += __shfl_xor(a00, d, 64);
            a01 += __shfl_xor(a01, d, 64);
            a10 += __shfl_xor(a10, d, 64);
            a11 += __shfl_xor(a11, d, 64);
        }
    }
    if (lane < 8) {
        agg[(size_t)n * 16 + f]     = packbf(a00, a01);
        agg[(size_t)n * 16 + 8 + f] = packbf(a10, a11);
    }
}

// ---- gather_agg layers 1..3: packed h rows (64 uints = 256 B, L2-resident)
__global__ void gather_agg(const unsigned* __restrict__ hp, const int* __restrict__ offs,
                           const int* __restrict__ csr_src, const float2* __restrict__ gauss,
                           unsigned* __restrict__ agg) {
    int tid = threadIdx.x;
    int lane = tid & 63;
    int n = blockIdx.x * 4 + (tid >> 6);
    if (n >= Nn) return;
    int s0 = offs[n], s1 = offs[n + 1];
    float a00 = 0.f, a01 = 0.f, a10 = 0.f, a11 = 0.f;  // a[k][b]
    int p = s0;
    for (; p + 3 < s1; p += 4) {
        int sa = csr_src[p], sb = csr_src[p + 1], sc = csr_src[p + 2], sd = csr_src[p + 3];
        float2 ga = gauss[p], gb = gauss[p + 1], gc = gauss[p + 2], gd = gauss[p + 3];
        unsigned ua = hp[(size_t)sa * 64 + lane];
        unsigned ub = hp[(size_t)sb * 64 + lane];
        unsigned uc = hp[(size_t)sc * 64 + lane];
        unsigned ud = hp[(size_t)sd * 64 + lane];
        float xa0 = uf(ua << 16), xa1 = uf(ua & 0xFFFF0000u);
        float xb0 = uf(ub << 16), xb1 = uf(ub & 0xFFFF0000u);
        float xc0 = uf(uc << 16), xc1 = uf(uc & 0xFFFF0000u);
        float xd0 = uf(ud << 16), xd1 = uf(ud & 0xFFFF0000u);
        a00 += ga.x * xa0 + gb.x * xb0 + gc.x * xc0 + gd.x * xd0;
        a01 += ga.x * xa1 + gb.x * xb1 + gc.x * xc1 + gd.x * xd1;
        a10 += ga.y * xa0 + gb.y * xb0 + gc.y * xc0 + gd.y * xd0;
        a11 += ga.y * xa1 + gb.y * xb1 + gc.y * xc1 + gd.y * xd1;
    }
    for (; p < s1; ++p) {
        int sa = csr_src[p];
        float2 ga = gauss[p];
        unsigned ua = hp[(size_t)sa * 64 + lane];
        float xa0 = uf(ua << 16), xa1 = uf(ua & 0xFFFF0000u);
        a00 += ga.x * xa0; a01 += ga.x * xa1;
        a10 += ga.y * xa0; a11 += ga.y * xa1;
    }
    agg[(size_t)n * 128 + lane]      = packbf(a00, a01);
    agg[(size_t)n * 128 + 64 + lane] = packbf(a10, a11);
}

// ---- combine: per-node GEMM agg@G + prev@root + bias, ELU, fc reduce -----
// agg layout [n][k*FP+f] packed {b0,b1}; G[f*128 + k*64 + h]; root[f*64 + h]
// NOTE: partial unroll + generous VGPR budget — full unroll spilled to
// scratch (R10: 1.1 GB WRITE_SIZE from a kernel that stores 3.9 MB).
template<int FP>
__global__ __launch_bounds__(256, 2)
void combine_kernel(const unsigned* __restrict__ agg, const int* __restrict__ offs,
                    const unsigned* __restrict__ prevp, const float* __restrict__ G,
                    const float* __restrict__ root, const float* __restrict__ bias,
                    const float* __restrict__ fc_w, int l,
                    unsigned* __restrict__ hpout, float* __restrict__ node) {
    int tid = threadIdx.x;
    int h = tid & 63;
    int r = tid >> 6;
    int n0 = blockIdx.x * 4;
    int n = n0 + r;
    __shared__ unsigned s_agg[4][2 * FP];
    __shared__ unsigned s_prev[4][FP];
    for (int idx = tid; idx < 4 * 2 * FP; idx += 256) {
        int rr = idx / (2 * FP), ff = idx % (2 * FP);
        int gn = n0 + rr;
        s_agg[rr][ff] = (gn < Nn) ? agg[(size_t)gn * 2 * FP + ff] : 0u;
    }
    for (int idx = tid; idx < 4 * FP; idx += 256) {
        int rr = idx / FP, ff = idx % FP;
        int gn = n0 + rr;
        s_prev[rr][ff] = (gn < Nn) ? prevp[(size_t)gn * FP + ff] : 0u;
    }
    __syncthreads();
    if (n >= Nn) return;
    float dg = (float)(offs[n + 1] - offs[n]);
    if (dg < 1.f) dg = 1.f;
    float inv = 1.f / dg;
    float bv = bias[h];
    float aA0 = 0.f, aA1 = 0.f;
    float aR0 = bv, aR1 = bv;
#pragma unroll 8
    for (int f = 0; f < FP; ++f) {
        float rv = root[f * 64 + h];
        unsigned up = s_prev[r][f];
        aR0 = fmaf(uf(up << 16), rv, aR0);
        aR1 = fmaf(uf(up & 0xFFFF0000u), rv, aR1);
    }
#pragma unroll 8
    for (int f = 0; f < FP; ++f) {
        float gv0 = G[f * 128 + h];
        float gv1 = G[f * 128 + 64 + h];
        unsigned u0 = s_agg[r][f];
        unsigned u1 = s_agg[r][FP + f];
        aA0 = fmaf(uf(u0 << 16), gv0, aA0);
        aA1 = fmaf(uf(u0 & 0xFFFF0000u), gv0, aA1);
        aA0 = fmaf(uf(u1 << 16), gv1, aA0);
        aA1 = fmaf(uf(u1 & 0xFFFF0000u), gv1, aA1);
    }
    float val0 = fmaf(aA0, inv, aR0);
    float val1 = fmaf(aA1, inv, aR1);
    val0 = val0 > 0.f ? val0 : expm1f(val0);
    val1 = val1 > 0.f ? val1 : expm1f(val1);
    hpout[(size_t)n * 64 + h] = packbf(val0, val1);
    float fw = fc_w[h * Ll + l];
    float r0 = val0 * fw, r1 = val1 * fw;
#pragma unroll
    for (int off = 32; off; off >>= 1) {
        r0 += __shfl_down(r0, off, 64);
        r1 += __shfl_down(r1, off, 64);
    }
    if (h == 0) {
        if (l == 0) { node[n] = r0; node[Nn + n] = r1; }
        else        { node[n] += r0; node[Nn + n] += r1; }
    }
}

// ---- head ----------------------------------------------------------------

__global__ void lin1_kernel(const float* __restrict__ node, const float* __restrict__ w,
                            const float* __restrict__ fcb, float* __restrict__ h1acc) {
    int hfc = threadIdx.x;
    int n0 = blockIdx.x * 64;
    int nend = n0 + 64 < Nn ? n0 + 64 : Nn;
    float fb = fcb[0];
    float a0 = 0.f, a1 = 0.f;
    for (int n = n0; n < nend; ++n) {
        float wv = w[(size_t)n * HFCc + hfc];
        a0 += (node[n] + fb) * wv;
        a1 += (node[Nn + n] + fb) * wv;
    }
    atomicAdd(&h1acc[hfc], a0);
    atomicAdd(&h1acc[HFCc + hfc], a1);
}

__global__ void head_kernel(const float* __restrict__ h1acc, const float* __restrict__ l1b,
                            const float* __restrict__ w2, const float* __restrict__ b2,
                            float* __restrict__ out) {
    __shared__ float sh[HFCc];
    __shared__ float slog[NCc];
    __shared__ float s_lse;
    int tid = threadIdx.x;
    for (int b = 0; b < BSz; ++b) {
        float v = h1acc[b * HFCc + tid] + l1b[tid];
        v = v > 0.f ? v : expm1f(v);
        sh[tid] = v;
        __syncthreads();
        if (tid < NCc) {
            float s = b2[tid];
            for (int i = 0; i < HFCc; ++i) s += sh[i] * w2[i * NCc + tid];
            slog[tid] = s;
        }
        __syncthreads();
        if (tid == 0) {
            float m = slog[0];
            for (int c = 1; c < NCc; ++c) m = fmaxf(m, slog[c]);
            float se = 0.f;
            for (int c = 0; c < NCc; ++c) se += expf(slog[c] - m);
            s_lse = m + logf(se);
        }
        __syncthreads();
        if (tid < NCc) out[b * NCc + tid] = slog[tid] - s_lse;
        __syncthreads();
    }
}

extern "C" void kernel_launch(void* const* d_in, const int* in_sizes, int n_in,
                              void* d_out, int out_size, void* d_ws, size_t ws_size,
                              hipStream_t stream) {
    const float* x      = (const float*)d_in[0];
    const int*   ei     = (const int*)d_in[2];
    const float* pseudo = (const float*)d_in[3];
    const float* g1     = (const float*)d_in[4];
    const float* mu1    = (const float*)d_in[5];
    const float* sigma1 = (const float*)d_in[6];
    const float* root1  = (const float*)d_in[7];
    const float* b1     = (const float*)d_in[8];
    const float* gs     = (const float*)d_in[9];
    const float* mus    = (const float*)d_in[10];
    const float* sigmas = (const float*)d_in[11];
    const float* roots  = (const float*)d_in[12];
    const float* bs_p   = (const float*)d_in[13];
    const float* fc_w   = (const float*)d_in[14];
    const float* fc_b   = (const float*)d_in[15];
    const float* lin1_w = (const float*)d_in[16];
    const float* lin1_b = (const float*)d_in[17];
    const float* lin2_w = (const float*)d_in[18];
    const float* lin2_b = (const float*)d_in[19];
    float* out = (float*)d_out;

    const int* src = ei;
    const int* dst = ei + Ee;

    auto alignup = [](size_t v) { return (v + 255) & ~(size_t)255; };
    char* ws = (char*)d_ws;
    size_t off = 0;
    float*    node    = (float*)(ws + off);    off += alignup((size_t)BSz * Nn * 4);
    float*    h1acc   = (float*)(ws + off);    off += alignup((size_t)BSz * HFCc * 4);
    int*      offs    = (int*)(ws + off);      off += alignup((size_t)(Nn + 1) * 4);
    int*      cursor  = (int*)(ws + off);      off += alignup((size_t)Nn * 4);
    int*      loc     = (int*)(ws + off);      off += alignup((size_t)Nn * 4);
    int*      bsum    = (int*)(ws + off);      off += alignup((size_t)64 * 4);
    int*      csr_src = (int*)(ws + off);      off += alignup((size_t)Ee * 4);
    float2*   gauss   = (float2*)(ws + off);   off += alignup((size_t)Ll * Ee * 8);
    unsigned* xi      = (unsigned*)(ws + off); off += alignup((size_t)Nn * F_INc * 4);
    unsigned* agg     = (unsigned*)(ws + off); off += alignup((size_t)Nn * 128 * 4);
    unsigned* hpA     = (unsigned*)(ws + off); off += alignup((size_t)Nn * 64 * 4);
    unsigned* hpB     = (unsigned*)(ws + off); off += alignup((size_t)Nn * 64 * 4);
    (void)ws_size; (void)in_sizes; (void)n_in; (void)out_size;

    zero_kernel<<<NBLK, 256, 0, stream>>>(cursor, h1acc);
    count_kernel<<<(Ee + 255) / 256, 256, 0, stream>>>(dst, cursor);
    scan_local<<<NBLK, 256, 0, stream>>>(cursor, loc, bsum);
    scan_tops<<<1, 64, 0, stream>>>(bsum);
    scan_fix<<<NBLK, 256, 0, stream>>>(loc, bsum, offs, cursor);
    pack_x<<<(Nn * F_INc + 255) / 256, 256, 0, stream>>>(x, xi);
    fill_kernel<<<(Ee + 255) / 256, 256, 0, stream>>>(src, dst, pseudo, cursor, csr_src, gauss,
                                                      mu1, sigma1, mus, sigmas);

    int ngrid = (Nn + 3) / 4;

    // layer 0
    gather_agg0<<<ngrid, 256, 0, stream>>>(xi, offs, csr_src, gauss, agg);
    combine_kernel<F_INc><<<ngrid, 256, 0, stream>>>(agg, offs, xi, g1, root1, b1, fc_w,
                                                     0, hpA, node);
    // layers 1..3
    unsigned* prev = hpA;
    unsigned* next = hpB;
    for (int l = 1; l < Ll; ++l) {
        const float* G  = gs    + (size_t)(l - 1) * Hh * 128;
        const float* rt = roots + (size_t)(l - 1) * Hh * Hh;
        const float* bb = bs_p  + (size_t)(l - 1) * Hh;
        gather_agg<<<ngrid, 256, 0, stream>>>(prev, offs, csr_src, gauss + (size_t)l * Ee, agg);
        combine_kernel<Hh><<<ngrid, 256, 0, stream>>>(agg, offs, prev, G, rt, bb, fc_w,
                                                      l, next, node);
        unsigned* t = prev; prev = next; next = t;
    }

    lin1_kernel<<<(Nn + 63) / 64, 256, 0, stream>>>(node, lin1_w, fc_b, h1acc);
    head_kernel<<<1, HFCc, 0, stream>>>(h1acc, lin1_b, lin2_w, lin2_b, out);
}

// Round 12
// 226.890 us; speedup vs baseline: 10.6064x; 1.0597x over previous
//
#include <hip/hip_runtime.h>
#include <hip/hip_bf16.h>

#define BSz 2
#define Nn 15135
#define Ee 242160
#define F_INc 8
#define Hh 64
#define Ll 4
#define HFCc 256
#define NCc 10
#define EPSg 1e-15f
#define NBLK ((Nn + 255) / 256)   // 60 scan blocks

__device__ __forceinline__ float uf(unsigned u) { return __uint_as_float(u); }
__device__ __forceinline__ unsigned short bs16(float f) {
    unsigned b = __float_as_uint(f);
    return (unsigned short)((b + 0x7FFFu + ((b >> 16) & 1u)) >> 16);
}
__device__ __forceinline__ unsigned packbf(float a, float b) {
    return (unsigned)bs16(a) | ((unsigned)bs16(b) << 16);
}

// ---- init ----------------------------------------------------------------

__global__ void zero_kernel(int* __restrict__ cursor, float* __restrict__ h1acc) {
    int i = blockIdx.x * 256 + threadIdx.x;
    if (i < Nn) cursor[i] = 0;
    if (i < BSz * HFCc) h1acc[i] = 0.f;
}

// x (2,N,8) f32 -> xi[n*8+f] = packed bf16 {b0,b1}
__global__ void pack_x(const float* __restrict__ x, unsigned* __restrict__ xi) {
    int i = blockIdx.x * 256 + threadIdx.x;
    if (i < Nn * F_INc) xi[i] = packbf(x[i], x[(size_t)Nn * F_INc + i]);
}

// ---- CSR build ----------------------------------------------------------

__global__ void count_kernel(const int* __restrict__ dst, int* __restrict__ cnt) {
    int e = blockIdx.x * blockDim.x + threadIdx.x;
    if (e < Ee) atomicAdd(&cnt[dst[e]], 1);
}

__global__ void scan_local(const int* __restrict__ cnt, int* __restrict__ loc,
                           int* __restrict__ bsum) {
    int tid = threadIdx.x, lane = tid & 63, w = tid >> 6;
    int i = blockIdx.x * 256 + tid;
    __shared__ int ws[4];
    int v = (i < Nn) ? cnt[i] : 0;
    int incl = v;
#pragma unroll
    for (int d = 1; d < 64; d <<= 1) {
        int t = __shfl_up(incl, d, 64);
        if (lane >= d) incl += t;
    }
    if (lane == 63) ws[w] = incl;
    __syncthreads();
    int pre = 0;
    for (int ww = 0; ww < w; ++ww) pre += ws[ww];
    if (i < Nn) loc[i] = pre + incl - v;
    if (tid == 255) bsum[blockIdx.x] = pre + incl;
}

__global__ void scan_tops(int* __restrict__ bsum) {
    int lane = threadIdx.x;
    int v = (lane < NBLK) ? bsum[lane] : 0;
    int incl = v;
#pragma unroll
    for (int d = 1; d < 64; d <<= 1) {
        int t = __shfl_up(incl, d, 64);
        if (lane >= d) incl += t;
    }
    if (lane < NBLK) bsum[lane] = incl - v;
}

__global__ void scan_fix(const int* __restrict__ loc, const int* __restrict__ bsum,
                         int* __restrict__ offs, int* __restrict__ cursor) {
    int i = blockIdx.x * 256 + threadIdx.x;
    if (i < Nn) {
        int o = loc[i] + bsum[blockIdx.x];
        offs[i] = o;
        cursor[i] = o;
    }
    if (i == 0) offs[Nn] = Ee;
}

// fill CSR + per-layer gauss arrays gauss[l*E + p]
__global__ void fill_kernel(const int* __restrict__ src, const int* __restrict__ dst,
                            const float* __restrict__ pseudo, int* __restrict__ cursor,
                            int* __restrict__ csr_src, float2* __restrict__ gauss,
                            const float* __restrict__ mu1, const float* __restrict__ sigma1,
                            const float* __restrict__ mus, const float* __restrict__ sigmas) {
    int e = blockIdx.x * blockDim.x + threadIdx.x;
    if (e >= Ee) return;
    int p = atomicAdd(&cursor[dst[e]], 1);
    csr_src[p] = src[e];
    float2 ps = ((const float2*)pseudo)[e];
#pragma unroll
    for (int l = 0; l < Ll; ++l) {
        const float* mu = (l == 0) ? mu1 : mus + (l - 1) * 4;
        const float* sg = (l == 0) ? sigma1 : sigmas + (l - 1) * 4;
        float d00 = ps.x - mu[0], d01 = ps.y - mu[1];
        float d10 = ps.x - mu[2], d11 = ps.y - mu[3];
        float i00 = 1.f / (EPSg + sg[0] * sg[0]);
        float i01 = 1.f / (EPSg + sg[1] * sg[1]);
        float i10 = 1.f / (EPSg + sg[2] * sg[2]);
        float i11 = 1.f / (EPSg + sg[3] * sg[3]);
        float g0 = expf(-0.5f * (d00 * d00 * i00 + d01 * d01 * i01));
        float g1 = expf(-0.5f * (d10 * d10 * i10 + d11 * d11 * i11));
        gauss[(size_t)l * Ee + p] = make_float2(g0, g1);
    }
}

// ---- layer 0 fused: gather xi rows (8 uints) + combine, LDS handoff ------
__global__ __launch_bounds__(256, 2)
void layer0_fused(const unsigned* __restrict__ xi, const int* __restrict__ offs,
                  const int* __restrict__ csr_src, const float2* __restrict__ gauss,
                  const float* __restrict__ G, const float* __restrict__ root,
                  const float* __restrict__ bias, const float* __restrict__ fc_w,
                  unsigned* __restrict__ hpout, float* __restrict__ node) {
    int tid = threadIdx.x;
    int lane = tid & 63;
    int r = tid >> 6;
    int n0 = blockIdx.x * 4;
    int n = n0 + r;
    __shared__ unsigned s_agg[4][2 * F_INc];
    __shared__ unsigned s_x[4][F_INc];
    // stage this block's xi rows (for root term)
    for (int idx = tid; idx < 4 * F_INc; idx += 256) {
        int rr = idx / F_INc, ff = idx % F_INc;
        int gn = n0 + rr;
        s_x[rr][ff] = (gn < Nn) ? xi[(size_t)gn * F_INc + ff] : 0u;
    }
    // gather phase
    if (n < Nn) {
        int esub = lane >> 3, f = lane & 7;
        int s0 = offs[n], s1 = offs[n + 1];
        float a00 = 0.f, a01 = 0.f, a10 = 0.f, a11 = 0.f;  // a[k][b]
        if (s1 > s0) {
            int last = s1 - 1;
            for (int p0 = s0; p0 <= last; p0 += 8) {
                int p = p0 + esub;
                int pc = p < last ? p : last;
                float2 g = gauss[pc];
                if (p > last) { g.x = 0.f; g.y = 0.f; }
                unsigned u = xi[csr_src[pc] * F_INc + f];
                float x0 = uf(u << 16), x1 = uf(u & 0xFFFF0000u);
                a00 += g.x * x0; a01 += g.x * x1;
                a10 += g.y * x0; a11 += g.y * x1;
            }
#pragma unroll
            for (int d = 8; d <= 32; d <<= 1) {
                a00 += __shfl_xor(a00, d, 64);
                a01 += __shfl_xor(a01, d, 64);
                a10 += __shfl_xor(a10, d, 64);
                a11 += __shfl_xor(a11, d, 64);
            }
        }
        if (lane < 8) {
            s_agg[r][f]         = packbf(a00, a01);
            s_agg[r][F_INc + f] = packbf(a10, a11);
        }
    }
    __syncthreads();
    // combine phase
    if (n >= Nn) return;
    int h = lane;
    float dg = (float)(offs[n + 1] - offs[n]);
    if (dg < 1.f) dg = 1.f;
    float inv = 1.f / dg;
    float bv = bias[h];
    float aA0 = 0.f, aA1 = 0.f;
    float aR0 = bv, aR1 = bv;
#pragma unroll
    for (int f = 0; f < F_INc; ++f) {
        float rv = root[f * 64 + h];
        unsigned up = s_x[r][f];
        aR0 = fmaf(uf(up << 16), rv, aR0);
        aR1 = fmaf(uf(up & 0xFFFF0000u), rv, aR1);
        float gv0 = G[f * 128 + h];
        float gv1 = G[f * 128 + 64 + h];
        unsigned u0 = s_agg[r][f];
        unsigned u1 = s_agg[r][F_INc + f];
        aA0 = fmaf(uf(u0 << 16), gv0, aA0);
        aA1 = fmaf(uf(u0 & 0xFFFF0000u), gv0, aA1);
        aA0 = fmaf(uf(u1 << 16), gv1, aA0);
        aA1 = fmaf(uf(u1 & 0xFFFF0000u), gv1, aA1);
    }
    float val0 = fmaf(aA0, inv, aR0);
    float val1 = fmaf(aA1, inv, aR1);
    val0 = val0 > 0.f ? val0 : expm1f(val0);
    val1 = val1 > 0.f ? val1 : expm1f(val1);
    hpout[(size_t)n * 64 + h] = packbf(val0, val1);
    float fw = fc_w[h * Ll + 0];
    float r0 = val0 * fw, r1 = val1 * fw;
#pragma unroll
    for (int off = 32; off; off >>= 1) {
        r0 += __shfl_down(r0, off, 64);
        r1 += __shfl_down(r1, off, 64);
    }
    if (h == 0) { node[n] = r0; node[Nn + n] = r1; }
}

// ---- layers 1..3 fused: gather packed h rows (256 B) + combine -----------
__global__ __launch_bounds__(256, 2)
void layer_fused(const unsigned* __restrict__ hp, const int* __restrict__ offs,
                 const int* __restrict__ csr_src, const float2* __restrict__ gauss,
                 const float* __restrict__ G, const float* __restrict__ root,
                 const float* __restrict__ bias, const float* __restrict__ fc_w,
                 int l, unsigned* __restrict__ hpout, float* __restrict__ node) {
    int tid = threadIdx.x;
    int lane = tid & 63;
    int r = tid >> 6;
    int n0 = blockIdx.x * 4;
    int n = n0 + r;
    __shared__ unsigned s_agg[4][128];
    __shared__ unsigned s_prev[4][64];
    // stage this block's prev rows (for root term): 256 coalesced loads
    {
        int gn = n0 + r;
        s_prev[r][lane] = (gn < Nn) ? hp[(size_t)gn * 64 + lane] : 0u;
    }
    // gather phase (identical inner loop to R11 gather_agg)
    if (n < Nn) {
        int s0 = offs[n], s1 = offs[n + 1];
        float a00 = 0.f, a01 = 0.f, a10 = 0.f, a11 = 0.f;  // a[k][b]
        int p = s0;
        for (; p + 3 < s1; p += 4) {
            int sa = csr_src[p], sb = csr_src[p + 1], sc = csr_src[p + 2], sd = csr_src[p + 3];
            float2 ga = gauss[p], gb = gauss[p + 1], gc = gauss[p + 2], gd = gauss[p + 3];
            unsigned ua = hp[(size_t)sa * 64 + lane];
            unsigned ub = hp[(size_t)sb * 64 + lane];
            unsigned uc = hp[(size_t)sc * 64 + lane];
            unsigned ud = hp[(size_t)sd * 64 + lane];
            float xa0 = uf(ua << 16), xa1 = uf(ua & 0xFFFF0000u);
            float xb0 = uf(ub << 16), xb1 = uf(ub & 0xFFFF0000u);
            float xc0 = uf(uc << 16), xc1 = uf(uc & 0xFFFF0000u);
            float xd0 = uf(ud << 16), xd1 = uf(ud & 0xFFFF0000u);
            a00 += ga.x * xa0 + gb.x * xb0 + gc.x * xc0 + gd.x * xd0;
            a01 += ga.x * xa1 + gb.x * xb1 + gc.x * xc1 + gd.x * xd1;
            a10 += ga.y * xa0 + gb.y * xb0 + gc.y * xc0 + gd.y * xd0;
            a11 += ga.y * xa1 + gb.y * xb1 + gc.y * xc1 + gd.y * xd1;
        }
        for (; p < s1; ++p) {
            int sa = csr_src[p];
            float2 ga = gauss[p];
            unsigned ua = hp[(size_t)sa * 64 + lane];
            float xa0 = uf(ua << 16), xa1 = uf(ua & 0xFFFF0000u);
            a00 += ga.x * xa0; a01 += ga.x * xa1;
            a10 += ga.y * xa0; a11 += ga.y * xa1;
        }
        s_agg[r][lane]      = packbf(a00, a01);
        s_agg[r][64 + lane] = packbf(a10, a11);
    }
    __syncthreads();
    // combine phase (R11 combine body, partial unroll to avoid spill)
    if (n >= Nn) return;
    int h = lane;
    float dg = (float)(offs[n + 1] - offs[n]);
    if (dg < 1.f) dg = 1.f;
    float inv = 1.f / dg;
    float bv = bias[h];
    float aA0 = 0.f, aA1 = 0.f;
    float aR0 = bv, aR1 = bv;
#pragma unroll 8
    for (int f = 0; f < Hh; ++f) {
        float rv = root[f * 64 + h];
        unsigned up = s_prev[r][f];
        aR0 = fmaf(uf(up << 16), rv, aR0);
        aR1 = fmaf(uf(up & 0xFFFF0000u), rv, aR1);
    }
#pragma unroll 8
    for (int f = 0; f < Hh; ++f) {
        float gv0 = G[f * 128 + h];
        float gv1 = G[f * 128 + 64 + h];
        unsigned u0 = s_agg[r][f];
        unsigned u1 = s_agg[r][Hh + f];
        aA0 = fmaf(uf(u0 << 16), gv0, aA0);
        aA1 = fmaf(uf(u0 & 0xFFFF0000u), gv0, aA1);
        aA0 = fmaf(uf(u1 << 16), gv1, aA0);
        aA1 = fmaf(uf(u1 & 0xFFFF0000u), gv1, aA1);
    }
    float val0 = fmaf(aA0, inv, aR0);
    float val1 = fmaf(aA1, inv, aR1);
    val0 = val0 > 0.f ? val0 : expm1f(val0);
    val1 = val1 > 0.f ? val1 : expm1f(val1);
    hpout[(size_t)n * 64 + h] = packbf(val0, val1);
    float fw = fc_w[h * Ll + l];
    float r0 = val0 * fw, r1 = val1 * fw;
#pragma unroll
    for (int off = 32; off; off >>= 1) {
        r0 += __shfl_down(r0, off, 64);
        r1 += __shfl_down(r1, off, 64);
    }
    if (h == 0) { node[n] += r0; node[Nn + n] += r1; }
}

// ---- head ----------------------------------------------------------------

__global__ void lin1_kernel(const float* __restrict__ node, const float* __restrict__ w,
                            const float* __restrict__ fcb, float* __restrict__ h1acc) {
    int hfc = threadIdx.x;
    int n0 = blockIdx.x * 64;
    int nend = n0 + 64 < Nn ? n0 + 64 : Nn;
    float fb = fcb[0];
    float a0 = 0.f, a1 = 0.f;
    for (int n = n0; n < nend; ++n) {
        float wv = w[(size_t)n * HFCc + hfc];
        a0 += (node[n] + fb) * wv;
        a1 += (node[Nn + n] + fb) * wv;
    }
    atomicAdd(&h1acc[hfc], a0);
    atomicAdd(&h1acc[HFCc + hfc], a1);
}

__global__ void head_kernel(const float* __restrict__ h1acc, const float* __restrict__ l1b,
                            const float* __restrict__ w2, const float* __restrict__ b2,
                            float* __restrict__ out) {
    __shared__ float sh[HFCc];
    __shared__ float slog[NCc];
    __shared__ float s_lse;
    int tid = threadIdx.x;
    for (int b = 0; b < BSz; ++b) {
        float v = h1acc[b * HFCc + tid] + l1b[tid];
        v = v > 0.f ? v : expm1f(v);
        sh[tid] = v;
        __syncthreads();
        if (tid < NCc) {
            float s = b2[tid];
            for (int i = 0; i < HFCc; ++i) s += sh[i] * w2[i * NCc + tid];
            slog[tid] = s;
        }
        __syncthreads();
        if (tid == 0) {
            float m = slog[0];
            for (int c = 1; c < NCc; ++c) m = fmaxf(m, slog[c]);
            float se = 0.f;
            for (int c = 0; c < NCc; ++c) se += expf(slog[c] - m);
            s_lse = m + logf(se);
        }
        __syncthreads();
        if (tid < NCc) out[b * NCc + tid] = slog[tid] - s_lse;
        __syncthreads();
    }
}

extern "C" void kernel_launch(void* const* d_in, const int* in_sizes, int n_in,
                              void* d_out, int out_size, void* d_ws, size_t ws_size,
                              hipStream_t stream) {
    const float* x      = (const float*)d_in[0];
    const int*   ei     = (const int*)d_in[2];
    const float* pseudo = (const float*)d_in[3];
    const float* g1     = (const float*)d_in[4];
    const float* mu1    = (const float*)d_in[5];
    const float* sigma1 = (const float*)d_in[6];
    const float* root1  = (const float*)d_in[7];
    const float* b1     = (const float*)d_in[8];
    const float* gs     = (const float*)d_in[9];
    const float* mus    = (const float*)d_in[10];
    const float* sigmas = (const float*)d_in[11];
    const float* roots  = (const float*)d_in[12];
    const float* bs_p   = (const float*)d_in[13];
    const float* fc_w   = (const float*)d_in[14];
    const float* fc_b   = (const float*)d_in[15];
    const float* lin1_w = (const float*)d_in[16];
    const float* lin1_b = (const float*)d_in[17];
    const float* lin2_w = (const float*)d_in[18];
    const float* lin2_b = (const float*)d_in[19];
    float* out = (float*)d_out;

    const int* src = ei;
    const int* dst = ei + Ee;

    auto alignup = [](size_t v) { return (v + 255) & ~(size_t)255; };
    char* ws = (char*)d_ws;
    size_t off = 0;
    float*    node    = (float*)(ws + off);    off += alignup((size_t)BSz * Nn * 4);
    float*    h1acc   = (float*)(ws + off);    off += alignup((size_t)BSz * HFCc * 4);
    int*      offs    = (int*)(ws + off);      off += alignup((size_t)(Nn + 1) * 4);
    int*      cursor  = (int*)(ws + off);      off += alignup((size_t)Nn * 4);
    int*      loc     = (int*)(ws + off);      off += alignup((size_t)Nn * 4);
    int*      bsum    = (int*)(ws + off);      off += alignup((size_t)64 * 4);
    int*      csr_src = (int*)(ws + off);      off += alignup((size_t)Ee * 4);
    float2*   gauss   = (float2*)(ws + off);   off += alignup((size_t)Ll * Ee * 8);
    unsigned* xi      = (unsigned*)(ws + off); off += alignup((size_t)Nn * F_INc * 4);
    unsigned* hpA     = (unsigned*)(ws + off); off += alignup((size_t)Nn * 64 * 4);
    unsigned* hpB     = (unsigned*)(ws + off); off += alignup((size_t)Nn * 64 * 4);
    (void)ws_size; (void)in_sizes; (void)n_in; (void)out_size;

    zero_kernel<<<NBLK, 256, 0, stream>>>(cursor, h1acc);
    count_kernel<<<(Ee + 255) / 256, 256, 0, stream>>>(dst, cursor);
    scan_local<<<NBLK, 256, 0, stream>>>(cursor, loc, bsum);
    scan_tops<<<1, 64, 0, stream>>>(bsum);
    scan_fix<<<NBLK, 256, 0, stream>>>(loc, bsum, offs, cursor);
    pack_x<<<(Nn * F_INc + 255) / 256, 256, 0, stream>>>(x, xi);
    fill_kernel<<<(Ee + 255) / 256, 256, 0, stream>>>(src, dst, pseudo, cursor, csr_src, gauss,
                                                      mu1, sigma1, mus, sigmas);

    int ngrid = (Nn + 3) / 4;

    layer0_fused<<<ngrid, 256, 0, stream>>>(xi, offs, csr_src, gauss, g1, root1, b1, fc_w,
                                            hpA, node);
    unsigned* prev = hpA;
    unsigned* next = hpB;
    for (int l = 1; l < Ll; ++l) {
        const float* G  = gs    + (size_t)(l - 1) * Hh * 128;
        const float* rt = roots + (size_t)(l - 1) * Hh * Hh;
        const float* bb = bs_p  + (size_t)(l - 1) * Hh;
        layer_fused<<<ngrid, 256, 0, stream>>>(prev, offs, csr_src, gauss + (size_t)l * Ee,
                                               G, rt, bb, fc_w, l, next, node);
        unsigned* t = prev; prev = next; next = t;
    }

    lin1_kernel<<<(Nn + 63) / 64, 256, 0, stream>>>(node, lin1_w, fc_b, h1acc);
    head_kernel<<<1, HFCc, 0, stream>>>(h1acc, lin1_b, lin2_w, lin2_b, out);
}